// Round 1
// baseline (126.439 us; speedup 1.0000x reference)
//
#include <hip/hip_runtime.h>

// 5x5 local attention, B=2 H=128 W=128 C=64 BIN=64, fp32.
//
// R5: TIMING-DISCRIMINATION PROBE. Kernel body is byte-identical to R4
// (the harness-verified 82.7/85.5 us version). The only change: the
// kernel is launched 4x back-to-back. The launches are idempotent
// (deterministic, no workspace use, output rewritten identically), so
// verification is unaffected. Read-out: kernel_serial_time = (dur_us -
// 85.5) / 3. This separates "timed window dominated by the 2x268MB
// harness poison fills" (dur -> ~110us) from "kernel itself is ~41us of
// the window" (dur -> ~205us), which the current rocprof top-5 (all
// fillBufferAligned) cannot distinguish.
//
// R4 notes (unchanged):
//  - Scores: zero-padded ref tile in LDS (25.6 KB), 25 ds_read_b128/wave.
//  - Values: read straight from global (L1/L2) — VMEM pipe in parallel
//    with LDS pipe across resident blocks. Interior blocks (72.7%) use
//    pure affine addresses. Edge blocks keep clamps + weight masks.
//  - Single __syncthreads; staging index via incremental wrap.

#define BB 2
#define HH 128
#define WW 128
#define CC 64
#define KK 5
#define PAD 2
#define TC 20            // tile cols = 16 + 2*PAD
#define NV (KK * TC)     // 100 column-vectors per tile

template <int CTRL>
__device__ __forceinline__ float dpp_add(float v) {
    int r = __builtin_amdgcn_update_dpp(0, __float_as_int(v), CTRL, 0xF, 0xF, true);
    return v + __int_as_float(r);
}

// Sum across the 16 lanes of a DPP row (== one pixel group).
__device__ __forceinline__ float group16_sum(float v) {
    v = dpp_add<0xB1>(v);    // quad_perm xor 1
    v = dpp_add<0x4E>(v);    // quad_perm xor 2
    v = dpp_add<0x124>(v);   // row_ror:4
    v = dpp_add<0x128>(v);   // row_ror:8
    return v;
}

__global__ __launch_bounds__(256, 4) void local_attn_kernel(
    const float* __restrict__ mainp,
    const float* __restrict__ refp,
    const float* __restrict__ refvp,
    float* __restrict__ outp)
{
    __shared__ float reft[NV * CC];   // 25.6 KB zero-padded ref tile

    const int tid    = threadIdx.x;
    const int lane16 = tid & 15;      // channel-quad index
    const int pix    = tid >> 4;      // local pixel 0..15
    const int seg    = blockIdx.x;    // 0..2047
    const int wseg   = seg & 7;
    const int h      = (seg >> 3) & (HH - 1);   // uniform per block
    const int b      = seg >> 10;
    const int w0     = wseg * 16;
    const int w      = w0 + pix;
    const int cb     = lane16 * 4;

    const size_t pbase = (((size_t)(b * HH + h)) * WW + w) * CC + cb;
    const float4 m4 = *reinterpret_cast<const float4*>(mainp + pbase);

    const bool interior = (wseg >= 1) & (wseg <= 6) & (h >= PAD) & (h < HH - PAD);

    // ---- stage zero-padded ref tile: vector v=(r,c) -> reft[v*CC] ----
    // Thread (pix, lane16) stages channel-quad cb of vectors v = pix + 16*i.
    {
        int r = 0, c = pix;            // v = pix, then v += 16 with wrap
        if (interior) {
            const float* srcb =
                refp + (((size_t)(b * HH + h - PAD)) * WW + (w0 - PAD)) * CC + cb;
            #pragma unroll
            for (int i = 0; i < 7; ++i) {
                const int v = pix + 16 * i;
                if (v < NV) {
                    const float4 d = *reinterpret_cast<const float4*>(
                        srcb + ((size_t)(r * WW + c)) * CC);
                    *reinterpret_cast<float4*>(reft + (size_t)v * CC + cb) = d;
                }
                c += 16; const bool wr = (c >= TC); c = wr ? c - TC : c; r += wr;
            }
        } else {
            #pragma unroll
            for (int i = 0; i < 7; ++i) {
                const int v = pix + 16 * i;
                if (v < NV) {
                    const int hg  = h + r - PAD;
                    const int wg  = w0 + c - PAD;
                    const int hgc = min(max(hg, 0), HH - 1);
                    const int wgc = min(max(wg, 0), WW - 1);
                    const float4 d = *reinterpret_cast<const float4*>(
                        refp + (((size_t)(b * HH + hgc)) * WW + wgc) * CC + cb);
                    const bool ok = ((unsigned)hg < (unsigned)HH) &
                                    ((unsigned)wg < (unsigned)WW);
                    float4 z;
                    z.x = ok ? d.x : 0.0f;
                    z.y = ok ? d.y : 0.0f;
                    z.z = ok ? d.z : 0.0f;
                    z.w = ok ? d.w : 0.0f;
                    *reinterpret_cast<float4*>(reft + (size_t)v * CC + cb) = z;
                }
                c += 16; const bool wr = (c >= TC); c = wr ? c - TC : c; r += wr;
            }
        }
    }
    __syncthreads();

    // ---- scores: 25 ds_read_b128 with immediate offsets ----
    const float* tbase = reft + pix * CC + cb;
    float sc[KK * KK];
    #pragma unroll
    for (int r = 0; r < KK; ++r) {
        #pragma unroll
        for (int dj = 0; dj < KK; ++dj) {
            const float4 t =
                *reinterpret_cast<const float4*>(tbase + (r * TC + dj) * CC);
            sc[r * KK + dj] = m4.x * t.x + m4.y * t.y + m4.z * t.z + m4.w * t.w;
        }
    }

    // ---- reduce each score across the 16-lane group (VALU/DPP) ----
    #pragma unroll
    for (int p = 0; p < KK * KK; ++p) sc[p] = group16_sum(sc[p]);

    // ---- softmax over 25 (padded entries exactly 0, included) ----
    float mx = sc[0];
    #pragma unroll
    for (int p = 1; p < KK * KK; ++p) mx = fmaxf(mx, sc[p]);
    float ssum = 0.0f;
    #pragma unroll
    for (int p = 0; p < KK * KK; ++p) { sc[p] = __expf(sc[p] - mx); ssum += sc[p]; }
    const float inv = 1.0f / ssum;     // applied to acc at the end

    // ---- values from GLOBAL (VMEM pipe, parallel to LDS pipe) ----
    float4 acc = make_float4(0.f, 0.f, 0.f, 0.f);
    if (interior) {
        const float* vb = refvp + pbase;
        #pragma unroll
        for (int di = 0; di < KK; ++di) {
            const float* row = vb + (ptrdiff_t)(di - PAD) * (WW * CC);
            #pragma unroll
            for (int dj = 0; dj < KK; ++dj) {
                const float4 v4 =
                    *reinterpret_cast<const float4*>(row + (dj - PAD) * CC);
                const float a = sc[di * KK + dj];
                acc.x += a * v4.x;
                acc.y += a * v4.y;
                acc.z += a * v4.z;
                acc.w += a * v4.w;
            }
        }
    } else {
        int   wwc[KK];
        float wokf[KK];
        #pragma unroll
        for (int dj = 0; dj < KK; ++dj) {
            const int ww_ = w + dj - PAD;
            wwc[dj]  = min(max(ww_, 0), WW - 1);
            wokf[dj] = ((unsigned)ww_ < (unsigned)WW) ? 1.0f : 0.0f;
        }
        #pragma unroll
        for (int di = 0; di < KK; ++di) {
            const int hh_  = h + di - PAD;
            const int hhc  = min(max(hh_, 0), HH - 1);
            const float hokf = ((unsigned)hh_ < (unsigned)HH) ? 1.0f : 0.0f;
            const float* row = refvp + (((size_t)(b * HH + hhc)) * WW) * CC + cb;
            #pragma unroll
            for (int dj = 0; dj < KK; ++dj) {
                const float4 v4 =
                    *reinterpret_cast<const float4*>(row + (size_t)wwc[dj] * CC);
                const float a = sc[di * KK + dj] * hokf * wokf[dj];
                acc.x += a * v4.x;
                acc.y += a * v4.y;
                acc.z += a * v4.z;
                acc.w += a * v4.w;
            }
        }
    }
    acc.x *= inv; acc.y *= inv; acc.z *= inv; acc.w *= inv;

    *reinterpret_cast<float4*>(outp + pbase) = acc;
}

extern "C" void kernel_launch(void* const* d_in, const int* in_sizes, int n_in,
                              void* d_out, int out_size, void* d_ws, size_t ws_size,
                              hipStream_t stream) {
    const float* mainp = (const float*)d_in[0];
    const float* refp  = (const float*)d_in[1];
    const float* refvp = (const float*)d_in[2];
    float* outp        = (float*)d_out;

    const int blocks = BB * HH * (WW / 16);  // 2048

    // R5 probe: 4 identical launches. Idempotent (same inputs -> same
    // output, rewritten in place). kernel_serial_us = (dur_us - base)/3.
    #pragma unroll
    for (int rep = 0; rep < 4; ++rep) {
        local_attn_kernel<<<blocks, 256, 0, stream>>>(mainp, refp, refvp, outp);
    }
}

// Round 2
// 84.672 us; speedup vs baseline: 1.4933x; 1.4933x over previous
//
#include <hip/hip_runtime.h>
#include <cstdint>

// 5x5 local attention, B=2 H=128 W=128 C=64 BIN=64, fp32.
//
// R6: single-burst staging. The bench window times the kernel COLD (a
// 268MB poison fill flushes L2/L3 immediately before it; probe R5 showed
// cold=40us vs warm=13.7us). R4 paid two serialized congested-miss
// rounds: ref staging, then register-batched value loads after softmax.
// R6 issues ALL global traffic up front via global_load_lds (width=16,
// no VGPR round-trip):
//   - interior blocks: ref AND value tiles direct-to-LDS, 14 loads, zero
//     staging VALU, one barrier, one miss round.
//   - edge blocks: value tile via clamped direct-to-LDS (garbage entries
//     are killed by the existing 0-weight masks — exact); ref tile keeps
//     the register zero-select path (exact zero-pad semantics for scores).
//   - value FMAs now read LDS (same 25-immediate-offset pattern as the
//     score reads; same benign 2-way banking).
// LDS 2x25.6KB = 51.2KB -> 3 blocks/CU.
// Semantics identical to R4: zero-padded scores enter softmax; OOB value
// weight forced to 0. Math order unchanged -> bitwise-identical output.

#define BB 2
#define HH 128
#define WW 128
#define CC 64
#define KK 5
#define PAD 2
#define TC 20            // tile cols = 16 + 2*PAD
#define NV (KK * TC)     // 100 column-vectors per tile

template <int CTRL>
__device__ __forceinline__ float dpp_add(float v) {
    int r = __builtin_amdgcn_update_dpp(0, __float_as_int(v), CTRL, 0xF, 0xF, true);
    return v + __int_as_float(r);
}

// Sum across the 16 lanes of a DPP row (== one pixel group).
__device__ __forceinline__ float group16_sum(float v) {
    v = dpp_add<0xB1>(v);    // quad_perm xor 1
    v = dpp_add<0x4E>(v);    // quad_perm xor 2
    v = dpp_add<0x124>(v);   // row_ror:4
    v = dpp_add<0x128>(v);   // row_ror:8
    return v;
}

// Direct global->LDS, 16B per lane. LDS dest is wave-uniform base +
// lane*16 (the staging walk below produces exactly that layout).
// Casts follow the CK pattern: int->ptr casts into addrspace(1)/(3);
// generic LDS pointer's low 32 bits are the DS offset.
__device__ __forceinline__ void lds_load16(const float* g, float* l) {
    __builtin_amdgcn_global_load_lds(
        (const __attribute__((address_space(1))) void*)(uintptr_t)g,
        (__attribute__((address_space(3))) void*)(uint32_t)(uintptr_t)l,
        16, 0, 0);
}

__global__ __launch_bounds__(256, 3) void local_attn_kernel(
    const float* __restrict__ mainp,
    const float* __restrict__ refp,
    const float* __restrict__ refvp,
    float* __restrict__ outp)
{
    __shared__ float reft[NV * CC];   // 25.6 KB zero-padded ref tile
    __shared__ float valt[NV * CC];   // 25.6 KB value tile (clamped at edges)

    const int tid    = threadIdx.x;
    const int lane16 = tid & 15;      // channel-quad index
    const int pix    = tid >> 4;      // local pixel 0..15
    const int seg    = blockIdx.x;    // 0..2047
    const int wseg   = seg & 7;
    const int h      = (seg >> 3) & (HH - 1);   // uniform per block
    const int b      = seg >> 10;
    const int w0     = wseg * 16;
    const int w      = w0 + pix;
    const int cb     = lane16 * 4;

    const size_t pbase = (((size_t)(b * HH + h)) * WW + w) * CC + cb;
    const float4 m4 = *reinterpret_cast<const float4*>(mainp + pbase);

    const bool interior = (wseg >= 1) & (wseg <= 6) & (h >= PAD) & (h < HH - PAD);
    const int v0base = (tid >> 6) * 4;   // wave-uniform LDS group base

    // ---- stage tiles: vector v=(r,c) -> tile[v*CC], one miss round ----
    // Thread (pix, lane16) sources channel-quad cb of v = pix + 16*i;
    // within a wave that is dest = (v0*CC)*4B + lane*16B, as required.
    {
        int r = 0, c = pix;            // v = pix, then v += 16 with wrap
        if (interior) {
            const size_t obase =
                (((size_t)(b * HH + h - PAD)) * WW + (w0 - PAD)) * CC + cb;
            #pragma unroll
            for (int i = 0; i < 7; ++i) {
                const int v0 = v0base + 16 * i;      // wave-uniform
                if (v0 < NV) {
                    const size_t off = obase + ((size_t)(r * WW + c)) * CC;
                    lds_load16(refp  + off, reft + (size_t)v0 * CC);
                    lds_load16(refvp + off, valt + (size_t)v0 * CC);
                }
                c += 16; const bool wr = (c >= TC); c = wr ? c - TC : c; r += wr;
            }
        } else {
            #pragma unroll
            for (int i = 0; i < 7; ++i) {
                const int v0 = v0base + 16 * i;      // wave-uniform
                if (v0 < NV) {
                    const int v   = pix + 16 * i;    // per-thread vector
                    const int hg  = h + r - PAD;
                    const int wg  = w0 + c - PAD;
                    const int hgc = min(max(hg, 0), HH - 1);
                    const int wgc = min(max(wg, 0), WW - 1);
                    const size_t coff =
                        (((size_t)(b * HH + hgc)) * WW + wgc) * CC + cb;
                    // value tile: clamped direct-to-LDS (masked later)
                    lds_load16(refvp + coff, valt + (size_t)v0 * CC);
                    // ref tile: register load + exact zero-pad select
                    const float4 d =
                        *reinterpret_cast<const float4*>(refp + coff);
                    const bool ok = ((unsigned)hg < (unsigned)HH) &
                                    ((unsigned)wg < (unsigned)WW);
                    float4 z;
                    z.x = ok ? d.x : 0.0f;
                    z.y = ok ? d.y : 0.0f;
                    z.z = ok ? d.z : 0.0f;
                    z.w = ok ? d.w : 0.0f;
                    *reinterpret_cast<float4*>(reft + (size_t)v * CC + cb) = z;
                }
                c += 16; const bool wr = (c >= TC); c = wr ? c - TC : c; r += wr;
            }
        }
    }
    __syncthreads();   // drains vmcnt (global_load_lds) + lgkmcnt

    // ---- scores: 25 ds_read_b128 with immediate offsets ----
    const float* tbase = reft + pix * CC + cb;
    float sc[KK * KK];
    #pragma unroll
    for (int r = 0; r < KK; ++r) {
        #pragma unroll
        for (int dj = 0; dj < KK; ++dj) {
            const float4 t =
                *reinterpret_cast<const float4*>(tbase + (r * TC + dj) * CC);
            sc[r * KK + dj] = m4.x * t.x + m4.y * t.y + m4.z * t.z + m4.w * t.w;
        }
    }

    // ---- reduce each score across the 16-lane group (VALU/DPP) ----
    #pragma unroll
    for (int p = 0; p < KK * KK; ++p) sc[p] = group16_sum(sc[p]);

    // ---- softmax over 25 (padded entries exactly 0, included) ----
    float mx = sc[0];
    #pragma unroll
    for (int p = 1; p < KK * KK; ++p) mx = fmaxf(mx, sc[p]);
    float ssum = 0.0f;
    #pragma unroll
    for (int p = 0; p < KK * KK; ++p) { sc[p] = __expf(sc[p] - mx); ssum += sc[p]; }
    const float inv = 1.0f / ssum;     // applied to acc at the end

    // ---- values from LDS tile (pixel pix, offset (di,dj) -> v=di*TC+pix+dj) ----
    const float* vtb = valt + pix * CC + cb;
    float4 acc = make_float4(0.f, 0.f, 0.f, 0.f);
    if (interior) {
        #pragma unroll
        for (int di = 0; di < KK; ++di) {
            #pragma unroll
            for (int dj = 0; dj < KK; ++dj) {
                const float4 v4 =
                    *reinterpret_cast<const float4*>(vtb + (di * TC + dj) * CC);
                const float a = sc[di * KK + dj];
                acc.x += a * v4.x;
                acc.y += a * v4.y;
                acc.z += a * v4.z;
                acc.w += a * v4.w;
            }
        }
    } else {
        float wokf[KK];
        #pragma unroll
        for (int dj = 0; dj < KK; ++dj) {
            const int ww_ = w + dj - PAD;
            wokf[dj] = ((unsigned)ww_ < (unsigned)WW) ? 1.0f : 0.0f;
        }
        #pragma unroll
        for (int di = 0; di < KK; ++di) {
            const int hh_   = h + di - PAD;
            const float hokf = ((unsigned)hh_ < (unsigned)HH) ? 1.0f : 0.0f;
            #pragma unroll
            for (int dj = 0; dj < KK; ++dj) {
                const float4 v4 =
                    *reinterpret_cast<const float4*>(vtb + (di * TC + dj) * CC);
                const float a = sc[di * KK + dj] * hokf * wokf[dj];
                acc.x += a * v4.x;
                acc.y += a * v4.y;
                acc.z += a * v4.z;
                acc.w += a * v4.w;
            }
        }
    }
    acc.x *= inv; acc.y *= inv; acc.z *= inv; acc.w *= inv;

    *reinterpret_cast<float4*>(outp + pbase) = acc;
}

extern "C" void kernel_launch(void* const* d_in, const int* in_sizes, int n_in,
                              void* d_out, int out_size, void* d_ws, size_t ws_size,
                              hipStream_t stream) {
    const float* mainp = (const float*)d_in[0];
    const float* refp  = (const float*)d_in[1];
    const float* refvp = (const float*)d_in[2];
    float* outp        = (float*)d_out;

    const int blocks = BB * HH * (WW / 16);  // 2048
    local_attn_kernel<<<blocks, 256, 0, stream>>>(mainp, refp, refvp, outp);
}